// Round 8
// baseline (35.286 us; speedup 1.0000x reference)
//
#include <hip/hip_runtime.h>

#define NB 8
#define C_OUT 64
#define NK 11
#define HH 64
#define WW 64
#define NG 4
#define HW (HH*WW)
#define CH (C_OUT*NK)
#define SPLIT 2          // strips per (b,r) tile; 32 rows each (2 rows/thread)

typedef float f32x4 __attribute__((ext_vector_type(4)));

__global__ __launch_bounds__(256) void fused_addshift_kernel(
    const float* __restrict__ x,
    const int* __restrict__ perm_h,
    const int* __restrict__ perm_v,
    const int* __restrict__ sel_id,
    float* __restrict__ out)
{
    const int blk = blockIdx.x;          // ((b*C_OUT + r) * SPLIT) + strip
    const int strip = blk & (SPLIT - 1);
    const int br = blk >> 1;
    const int b = br >> 6;
    const int r = br & 63;

    __shared__ float c1[3][NK];
    __shared__ float c2[3][NK];
    __shared__ float cs[NK];
    __shared__ int ic1[3][NK], ic2[3][NK], ics[NK];

    const int tid = threadIdx.x;

    if (tid < 33) { ic1[tid / 11][tid % 11] = 0; ic2[tid / 11][tid % 11] = 0; }
    if (tid >= 33 && tid < 44) ics[tid - 33] = 0;
    __syncthreads();

    if (tid < 44) {
        int g = tid / 11, k = tid % 11;
        int m = (r * NK + k) % 3;
        int j1 = perm_h[(g * C_OUT + r) * NK + k] % NK;
        int j2 = perm_v[(g * C_OUT + r) * NK + k] % NK;
        atomicAdd(&ic1[m][j1], 1);
        atomicAdd(&ic2[m][j2], 1);
    } else if (tid < 48) {
        int g = tid - 44;
        int j = sel_id[g * C_OUT + r] % NK;
        atomicAdd(&ics[j], 1);
    }
    __syncthreads();
    if (tid < 33) {
        c1[tid / 11][tid % 11] = (float)ic1[tid / 11][tid % 11];
        c2[tid / 11][tid % 11] = (float)ic2[tid / 11][tid % 11];
    }
    if (tid >= 33 && tid < 44) cs[tid - 33] = (float)ics[tid - 33];
    __syncthreads();

    const float* xp = x + ((size_t)b * CH + (size_t)r * NK) * HW;
    float* o1 = out + ((size_t)b * C_OUT + r) * HW;
    float* o2 = o1 + (size_t)NB * C_OUT * HW;
    float* o3 = o2 + (size_t)NB * C_OUT * HW;

    // thread -> two adjacent rows x one float4: 16 lanes in w, 16 row-pair slots
    const int slot = tid >> 4;                 // 0..15
    const int w4 = (tid & 15) << 2;            // 0,4,...,60
    const int h0 = strip * 32 + slot * 2;      // even
    const int h1 = h0 + 1;
    const int hm1 = (h0 + HH - 1) & (HH - 1);
    const int hm2 = (h0 + HH - 2) & (HH - 1);
    const int wprev = (w4 + WW - 4) & (WW - 1);

    f32x4 acc1a = {0,0,0,0}, acc1b = {0,0,0,0};
    f32x4 acc2a = {0,0,0,0}, acc2b = {0,0,0,0};
    f32x4 accsa = {0,0,0,0}, accsb = {0,0,0,0};

    #pragma unroll
    for (int j = 0; j < NK; ++j) {
        const float* cp = xp + j * HW;
        // 4 rows at w4, 3 rows at wprev — all full aligned quads
        const f32x4 q0  = *reinterpret_cast<const f32x4*>(cp + h0  * WW + w4);    // row h0
        const f32x4 q1  = *reinterpret_cast<const f32x4*>(cp + h1  * WW + w4);    // row h0+1
        const f32x4 qm1 = *reinterpret_cast<const f32x4*>(cp + hm1 * WW + w4);    // row h0-1
        const f32x4 qm2 = *reinterpret_cast<const f32x4*>(cp + hm2 * WW + w4);    // row h0-2
        const f32x4 p0  = *reinterpret_cast<const f32x4*>(cp + h0  * WW + wprev); // row h0   @ w-4
        const f32x4 pm1 = *reinterpret_cast<const f32x4*>(cp + hm1 * WW + wprev); // row h0-1 @ w-4
        const f32x4 pm2 = *reinterpret_cast<const f32x4*>(cp + hm2 * WW + wprev); // row h0-2 @ w-4

        const float w10 = c1[0][j], w11 = c1[1][j], w12 = c1[2][j];
        const float w20 = c2[0][j], w21 = c2[1][j], w22 = c2[2][j];
        const float wss = cs[j];

        // ---- output row h0: X0=q0, XA=row h0-1 (w-2..w+1), XB=row h0-2 (w-1..w+2)
        {
            const float XAx = pm1.z, XAy = pm1.w, XAz = qm1.x, XAw = qm1.y;
            const float XBx = pm2.w, XBy = qm2.x, XBz = qm2.y, XBw = qm2.z;
            acc1a.x = fmaf(w10, q0.x, fmaf(w11, XAx, fmaf(w12, XBx, acc1a.x)));
            acc1a.y = fmaf(w10, q0.y, fmaf(w11, XAy, fmaf(w12, XBy, acc1a.y)));
            acc1a.z = fmaf(w10, q0.z, fmaf(w11, XAz, fmaf(w12, XBz, acc1a.z)));
            acc1a.w = fmaf(w10, q0.w, fmaf(w11, XAw, fmaf(w12, XBw, acc1a.w)));

            acc2a.x = fmaf(w20, q0.x, fmaf(w21, XBx, fmaf(w22, XAx, acc2a.x)));
            acc2a.y = fmaf(w20, q0.y, fmaf(w21, XBy, fmaf(w22, XAy, acc2a.y)));
            acc2a.z = fmaf(w20, q0.z, fmaf(w21, XBz, fmaf(w22, XAz, acc2a.z)));
            acc2a.w = fmaf(w20, q0.w, fmaf(w21, XBw, fmaf(w22, XAw, acc2a.w)));

            accsa.x = fmaf(wss, q0.x, accsa.x);
            accsa.y = fmaf(wss, q0.y, accsa.y);
            accsa.z = fmaf(wss, q0.z, accsa.z);
            accsa.w = fmaf(wss, q0.w, accsa.w);
        }
        // ---- output row h1: X0=q1, XA=row h0 (w-2..w+1), XB=row h0-1 (w-1..w+2)
        {
            const float XAx = p0.z,  XAy = p0.w,  XAz = q0.x,  XAw = q0.y;
            const float XBx = pm1.w, XBy = qm1.x, XBz = qm1.y, XBw = qm1.z;
            acc1b.x = fmaf(w10, q1.x, fmaf(w11, XAx, fmaf(w12, XBx, acc1b.x)));
            acc1b.y = fmaf(w10, q1.y, fmaf(w11, XAy, fmaf(w12, XBy, acc1b.y)));
            acc1b.z = fmaf(w10, q1.z, fmaf(w11, XAz, fmaf(w12, XBz, acc1b.z)));
            acc1b.w = fmaf(w10, q1.w, fmaf(w11, XAw, fmaf(w12, XBw, acc1b.w)));

            acc2b.x = fmaf(w20, q1.x, fmaf(w21, XBx, fmaf(w22, XAx, acc2b.x)));
            acc2b.y = fmaf(w20, q1.y, fmaf(w21, XBy, fmaf(w22, XAy, acc2b.y)));
            acc2b.z = fmaf(w20, q1.z, fmaf(w21, XBz, fmaf(w22, XAz, acc2b.z)));
            acc2b.w = fmaf(w20, q1.w, fmaf(w21, XBw, fmaf(w22, XAw, acc2b.w)));

            accsb.x = fmaf(wss, q1.x, accsb.x);
            accsb.y = fmaf(wss, q1.y, accsb.y);
            accsb.z = fmaf(wss, q1.z, accsb.z);
            accsb.w = fmaf(wss, q1.w, accsb.w);
        }
    }

    const int idx0 = h0 * WW + w4;
    const int idx1 = h1 * WW + w4;
    *reinterpret_cast<f32x4*>(o1 + idx0) = acc1a;
    *reinterpret_cast<f32x4*>(o1 + idx1) = acc1b;
    *reinterpret_cast<f32x4*>(o2 + idx0) = acc2a;
    *reinterpret_cast<f32x4*>(o2 + idx1) = acc2b;
    *reinterpret_cast<f32x4*>(o3 + idx0) = accsa;
    *reinterpret_cast<f32x4*>(o3 + idx1) = accsb;
}

extern "C" void kernel_launch(void* const* d_in, const int* in_sizes, int n_in,
                              void* d_out, int out_size, void* d_ws, size_t ws_size,
                              hipStream_t stream) {
    const float* x      = (const float*)d_in[0];
    const int* perm_h   = (const int*)d_in[1];
    const int* perm_v   = (const int*)d_in[2];
    const int* sel_id   = (const int*)d_in[3];
    float* out          = (float*)d_out;

    dim3 grid(NB * C_OUT * SPLIT);
    dim3 block(256);
    hipLaunchKernelGGL(fused_addshift_kernel, grid, block, 0, stream,
                       x, perm_h, perm_v, sel_id, out);
}

// Round 9
// 26.255 us; speedup vs baseline: 1.3440x; 1.3440x over previous
//
#include <hip/hip_runtime.h>

#define NB 8
#define C_OUT 64
#define NK 11
#define HH 64
#define WW 64
#define NG 4
#define HW (HH*WW)
#define CH (C_OUT*NK)
#define SPLIT 4          // strips per (b,r) tile; 16 rows each

typedef float f32x4 __attribute__((ext_vector_type(4)));

__global__ __launch_bounds__(256) void fused_addshift_kernel(
    const float* __restrict__ x,
    const int* __restrict__ perm_h,
    const int* __restrict__ perm_v,
    const int* __restrict__ sel_id,
    float* __restrict__ out)
{
    const int blk = blockIdx.x;          // ((b*C_OUT + r) * SPLIT) + strip
    const int strip = blk & (SPLIT - 1);
    const int br = blk >> 2;
    const int b = br >> 6;
    const int r = br & 63;

    __shared__ float c1[3][NK];
    __shared__ float c2[3][NK];
    __shared__ float cs[NK];
    __shared__ int ic1[3][NK], ic2[3][NK], ics[NK];

    const int tid = threadIdx.x;

    if (tid < 33) { ic1[tid / 11][tid % 11] = 0; ic2[tid / 11][tid % 11] = 0; }
    if (tid >= 33 && tid < 44) ics[tid - 33] = 0;
    __syncthreads();

    if (tid < 44) {
        int g = tid / 11, k = tid % 11;
        int m = (r * NK + k) % 3;
        int j1 = perm_h[(g * C_OUT + r) * NK + k] % NK;
        int j2 = perm_v[(g * C_OUT + r) * NK + k] % NK;
        atomicAdd(&ic1[m][j1], 1);
        atomicAdd(&ic2[m][j2], 1);
    } else if (tid < 48) {
        int g = tid - 44;
        int j = sel_id[g * C_OUT + r] % NK;
        atomicAdd(&ics[j], 1);
    }
    __syncthreads();
    if (tid < 33) {
        c1[tid / 11][tid % 11] = (float)ic1[tid / 11][tid % 11];
        c2[tid / 11][tid % 11] = (float)ic2[tid / 11][tid % 11];
    }
    if (tid >= 33 && tid < 44) cs[tid - 33] = (float)ics[tid - 33];
    __syncthreads();

    const float* xp = x + ((size_t)b * CH + (size_t)r * NK) * HW;
    float* o1 = out + ((size_t)b * C_OUT + r) * HW;
    float* o2 = o1 + (size_t)NB * C_OUT * HW;
    float* o3 = o2 + (size_t)NB * C_OUT * HW;

    // thread -> one float4: 16 threads per row, 16 rows per strip
    const int row_local = tid >> 4;            // 0..15
    const int w4 = (tid & 15) << 2;            // 0,4,...,60
    const int h   = strip * 16 + row_local;
    const int hm1 = (h + HH - 1) & (HH - 1);
    const int hm2 = (h + HH - 2) & (HH - 1);
    const int wprev = (w4 + WW - 4) & (WW - 1);

    f32x4 acc1 = {0.f, 0.f, 0.f, 0.f};
    f32x4 acc2 = {0.f, 0.f, 0.f, 0.f};
    f32x4 accs = {0.f, 0.f, 0.f, 0.f};

    // unroll 2 (not 11): keeps the live set ~10 in-flight quads so VGPR < 128
    // -> 5-6 waves/SIMD instead of 3 (round-2 full unroll = 132 VGPR = 3 waves)
    #pragma unroll 2
    for (int j = 0; j < NK; ++j) {
        const float* cp = xp + j * HW;
        const f32x4 X0 = *reinterpret_cast<const f32x4*>(cp + h   * WW + w4);
        const f32x4 a1 = *reinterpret_cast<const f32x4*>(cp + hm1 * WW + w4);
        const f32x4 b1 = *reinterpret_cast<const f32x4*>(cp + hm2 * WW + w4);
        const f32x4 a0 = *reinterpret_cast<const f32x4*>(cp + hm1 * WW + wprev);
        const f32x4 b0 = *reinterpret_cast<const f32x4*>(cp + hm2 * WW + wprev);

        // XA = row h-1, cols w-2..w+1 ; XB = row h-2, cols w-1..w+2
        const float XAx = a0.z, XAy = a0.w, XAz = a1.x, XAw = a1.y;
        const float XBx = b0.w, XBy = b1.x, XBz = b1.y, XBw = b1.z;

        const float w10 = c1[0][j], w11 = c1[1][j], w12 = c1[2][j];
        const float w20 = c2[0][j], w21 = c2[1][j], w22 = c2[2][j];
        const float wss = cs[j];

        acc1.x = fmaf(w10, X0.x, fmaf(w11, XAx, fmaf(w12, XBx, acc1.x)));
        acc1.y = fmaf(w10, X0.y, fmaf(w11, XAy, fmaf(w12, XBy, acc1.y)));
        acc1.z = fmaf(w10, X0.z, fmaf(w11, XAz, fmaf(w12, XBz, acc1.z)));
        acc1.w = fmaf(w10, X0.w, fmaf(w11, XAw, fmaf(w12, XBw, acc1.w)));

        acc2.x = fmaf(w20, X0.x, fmaf(w21, XBx, fmaf(w22, XAx, acc2.x)));
        acc2.y = fmaf(w20, X0.y, fmaf(w21, XBy, fmaf(w22, XAy, acc2.y)));
        acc2.z = fmaf(w20, X0.z, fmaf(w21, XBz, fmaf(w22, XAz, acc2.z)));
        acc2.w = fmaf(w20, X0.w, fmaf(w21, XBw, fmaf(w22, XAw, acc2.w)));

        accs.x = fmaf(wss, X0.x, accs.x);
        accs.y = fmaf(wss, X0.y, accs.y);
        accs.z = fmaf(wss, X0.z, accs.z);
        accs.w = fmaf(wss, X0.w, accs.w);
    }

    const int idx = h * WW + w4;
    *reinterpret_cast<f32x4*>(o1 + idx) = acc1;
    *reinterpret_cast<f32x4*>(o2 + idx) = acc2;
    *reinterpret_cast<f32x4*>(o3 + idx) = accs;
}

extern "C" void kernel_launch(void* const* d_in, const int* in_sizes, int n_in,
                              void* d_out, int out_size, void* d_ws, size_t ws_size,
                              hipStream_t stream) {
    const float* x      = (const float*)d_in[0];
    const int* perm_h   = (const int*)d_in[1];
    const int* perm_v   = (const int*)d_in[2];
    const int* sel_id   = (const int*)d_in[3];
    float* out          = (float*)d_out;

    dim3 grid(NB * C_OUT * SPLIT);
    dim3 block(256);
    hipLaunchKernelGGL(fused_addshift_kernel, grid, block, 0, stream,
                       x, perm_h, perm_v, sel_id, out);
}